// Round 7
// baseline (492.938 us; speedup 1.0000x reference)
//
#include <hip/hip_runtime.h>
#include <hip/hip_bf16.h>
#include <cstdint>
#include <cstddef>
#include <math.h>

#define NEG_SLOPE 0.2f

__device__ __forceinline__ float lrelu(float x) { return x > 0.f ? x : NEG_SLOPE * x; }

// Layouts:
//  xw    slice-major [8][N][16] (slice = ch>>4): k_agg pins slice->XCD (blockIdx%8),
//        per-XCD gather working set 3.2 MB < 4 MB L2 (verified: FETCH 320->70 MB r4).
//  as_h  head-major planes [4][N]: k_agg's on-the-fly e gather is one 4B L2 hit.
//  e = exp(lrelu(a_src+a_dst)) computed ON THE FLY in k_agg (r7): removes the
//  52.8 MB pk write (k_scatter) + 70 MB pk stream (k_agg FETCH) of r6.
//  Softmax normalization deferred to k_agg epilogue (linear). No max-subtraction
//  (|alpha|<~6, fp32-safe; validated absmax 1.5e-5).

// ---------------- GEMM: xw = x @ W1^T (slice-major) + fused a_src/a_dst ----------
__global__ __launch_bounds__(256) void k_gemm1(const float* __restrict__ x,
                                               const float* __restrict__ W1,
                                               const float* __restrict__ att_src,
                                               const float* __restrict__ att_dst,
                                               float* __restrict__ xw,
                                               float* __restrict__ as_h,
                                               float* __restrict__ a_dst, int N)
{
    __shared__ float As[32 * 68];    // As[kk*68 + r], r<64
    __shared__ float Bs[32 * 132];   // Bs[kk*132 + c], c<128
    const int tid = threadIdx.x;
    const int tx = tid & 31, ty = tid >> 5;
    const int bm = blockIdx.x * 64;
    float acc[8][4] = {};

    for (int k0 = 0; k0 < 128; k0 += 32) {
        #pragma unroll
        for (int t = tid; t < 512; t += 256) {          // A tile 64 rows x 32 k
            int r = t >> 3, q = t & 7;
            int n = bm + r;
            float4 f = make_float4(0.f, 0.f, 0.f, 0.f);
            if (n < N) f = *(const float4*)(x + (size_t)n * 128 + k0 + 4 * q);
            As[(4*q+0)*68 + r] = f.x; As[(4*q+1)*68 + r] = f.y;
            As[(4*q+2)*68 + r] = f.z; As[(4*q+3)*68 + r] = f.w;
        }
        #pragma unroll
        for (int t = tid; t < 1024; t += 256) {         // B tile 128 cols x 32 k
            int c = t >> 3, q = t & 7;
            float4 f = *(const float4*)(W1 + (size_t)c * 128 + k0 + 4 * q);
            Bs[(4*q+0)*132 + c] = f.x; Bs[(4*q+1)*132 + c] = f.y;
            Bs[(4*q+2)*132 + c] = f.z; Bs[(4*q+3)*132 + c] = f.w;
        }
        __syncthreads();
        #pragma unroll 8
        for (int kk = 0; kk < 32; kk++) {
            float4 a0 = *(const float4*)&As[kk * 68 + ty * 8];
            float4 a1 = *(const float4*)&As[kk * 68 + ty * 8 + 4];
            float4 b4 = *(const float4*)&Bs[kk * 132 + tx * 4];
            float a[8] = {a0.x, a0.y, a0.z, a0.w, a1.x, a1.y, a1.z, a1.w};
            float b[4] = {b4.x, b4.y, b4.z, b4.w};
            #pragma unroll
            for (int i = 0; i < 8; i++)
                #pragma unroll
                for (int j = 0; j < 4; j++) acc[i][j] = fmaf(a[i], b[j], acc[i][j]);
        }
        __syncthreads();
    }

    // thread owns cols ch = tx*4+j -> slice = tx>>2, head = tx>>3
    float asv[4], adv[4];
    #pragma unroll
    for (int j = 0; j < 4; j++) { asv[j] = att_src[tx*4+j]; adv[j] = att_dst[tx*4+j]; }
    const int slice = tx >> 2, cio = (tx & 3) * 4, head = tx >> 3;

    #pragma unroll
    for (int i = 0; i < 8; i++) {
        int n = bm + ty * 8 + i;
        float sv = 0.f, dv = 0.f;
        #pragma unroll
        for (int j = 0; j < 4; j++) {
            sv = fmaf(acc[i][j], asv[j], sv);
            dv = fmaf(acc[i][j], adv[j], dv);
        }
        #pragma unroll
        for (int off = 1; off < 8; off <<= 1) {
            sv += __shfl_xor(sv, off);
            dv += __shfl_xor(dv, off);
        }
        if (n < N) {
            *(float4*)&xw[((size_t)slice * N + n) * 16 + cio] =
                make_float4(acc[i][0], acc[i][1], acc[i][2], acc[i][3]);
            if ((tx & 7) == 0) {
                as_h[(size_t)head * N + n] = sv;     // head-major plane
                a_dst[n * 4 + head]       = dv;
            }
        }
    }
}

// ---------------- CSR build ----------------
__global__ void k_count(const int* __restrict__ ei, int E, int N, int* __restrict__ deg)
{
    int e = blockIdx.x * blockDim.x + threadIdx.x;
    if (e >= E + N) return;
    int d = (e < E) ? ei[(size_t)E + e] : (e - E);
    atomicAdd(&deg[d], 1);
}

__global__ __launch_bounds__(1024) void k_scanA(const int* __restrict__ deg,
                                                int* __restrict__ partial, int N, int R)
{
    __shared__ int ws[16];
    const int b = blockIdx.x, tid = threadIdx.x, w = tid >> 6, lane = tid & 63;
    int endi = (b + 1) * R; if (endi > N) endi = N;
    int s = 0;
    for (int i = b * R + tid; i < endi; i += 1024) s += deg[i];
    #pragma unroll
    for (int off = 1; off < 64; off <<= 1) s += __shfl_xor(s, off);
    if (lane == 0) ws[w] = s;
    __syncthreads();
    if (tid == 0) {
        int t = 0;
        #pragma unroll
        for (int i = 0; i < 16; i++) t += ws[i];
        partial[b] = t;
    }
}

__global__ void k_scanB(int* __restrict__ partial, int nblk,
                        int* __restrict__ row_ptr, int N)
{
    int lane = threadIdx.x;                      // 64 threads
    int orig = (lane < nblk) ? partial[lane] : 0;
    int v = orig;
    #pragma unroll
    for (int off = 1; off < 64; off <<= 1) {
        int u = __shfl_up(v, off);
        if (lane >= off) v += u;
    }
    if (lane < nblk) partial[lane] = v - orig;   // exclusive
    if (lane == 63) row_ptr[N] = v;
}

__global__ __launch_bounds__(1024) void k_scanC(const int* __restrict__ deg,
                                                const int* __restrict__ partial,
                                                int* __restrict__ row_ptr,
                                                int* __restrict__ cursor, int N, int R)
{
    __shared__ int wtot[16];
    __shared__ int s_carry;
    const int b = blockIdx.x, tid = threadIdx.x, w = tid >> 6, lane = tid & 63;
    if (tid == 0) s_carry = partial[b];
    __syncthreads();
    for (int off0 = 0; off0 < R; off0 += 1024) {
        int idx = b * R + off0 + tid;
        int v0 = (idx < N) ? deg[idx] : 0;
        int v = v0;
        #pragma unroll
        for (int off = 1; off < 64; off <<= 1) {
            int u = __shfl_up(v, off);
            if (lane >= off) v += u;
        }
        if (lane == 63) wtot[w] = v;
        __syncthreads();
        int carry = s_carry;
        if (w == 0) {
            int t = (lane < 16) ? wtot[lane] : 0;
            #pragma unroll
            for (int off = 1; off < 16; off <<= 1) {
                int u = __shfl_up(t, off);
                if (lane >= off) t += u;
            }
            if (lane < 16) wtot[lane] = t;
        }
        __syncthreads();
        int woff = (w > 0) ? wtot[w - 1] : 0;
        int excl = carry + woff + (v - v0);
        if (idx < N) { row_ptr[idx] = excl; cursor[idx] = excl; }
        __syncthreads();
        if (tid == 0) s_carry = carry + wtot[15];
        __syncthreads();
    }
}

// ---------------- scatter: csr_src only (4B/edge) ----------------
__global__ void k_scatter(const int* __restrict__ ei, int E, int N,
                          int* __restrict__ cursor, int* __restrict__ csr_src, int Et)
{
    int e = blockIdx.x * blockDim.x + threadIdx.x;
    if (e >= Et) return;
    int s, d;
    if (e < E) { s = ei[e]; d = ei[(size_t)E + e]; }
    else       { s = d = e - E; }
    int pos = atomicAdd(&cursor[d], 1);
    csr_src[pos] = s;
}

// ---------------- agg: one wave per (dst, slice); 16 edge-slots x 4 lanes/edge ---
// e computed on the fly from as_h plane (L2-resident 200KB) + wave-uniform adh.
// Denominator accumulated inline; normalize + relu(+b1)*W2 -> atomicAdd xw2.
__global__ __launch_bounds__(256) void k_agg(const float* __restrict__ xw,
                                             const float* __restrict__ as_h,
                                             const float* __restrict__ a_dst,
                                             const int* __restrict__ row_ptr,
                                             const int* __restrict__ csr_src,
                                             const float* __restrict__ b1,
                                             const float* __restrict__ W2,
                                             float* __restrict__ xw2, int N)
{
    const int slice = blockIdx.x & 7;
    const int dgrp  = blockIdx.x >> 3;
    const int wave  = threadIdx.x >> 6;
    const int lane  = threadIdx.x & 63;
    const int slot  = lane >> 2, li = lane & 3;       // 16 edge-slots x 4 ch-lanes
    const int d     = dgrp * 4 + wave;
    if (d >= N) return;
    const int head = slice >> 1;
    const float4* xs4 = (const float4*)(xw + (size_t)slice * N * 16);
    const float*  as  = as_h + (size_t)head * N;
    const float   adh = a_dst[d * 4 + head];

    const int beg = row_ptr[d];
    const int deg = row_ptr[d + 1] - beg;
    float4 acc = make_float4(0.f, 0.f, 0.f, 0.f);
    float csum = 0.f;
    #pragma unroll 2
    for (int k = slot; k < deg; k += 16) {
        int s = csr_src[beg + k];
        float e = __expf(lrelu(as[s] + adh));
        float4 v = xs4[(size_t)s * 4 + li];
        acc.x = fmaf(e, v.x, acc.x);
        acc.y = fmaf(e, v.y, acc.y);
        acc.z = fmaf(e, v.z, acc.z);
        acc.w = fmaf(e, v.w, acc.w);
        csum += e;
    }
    #pragma unroll
    for (int off = 4; off < 64; off <<= 1) {          // reduce over slots
        acc.x += __shfl_xor(acc.x, off);
        acc.y += __shfl_xor(acc.y, off);
        acc.z += __shfl_xor(acc.z, off);
        acc.w += __shfl_xor(acc.w, off);
        csum  += __shfl_xor(csum, off);
    }
    float4 bb = ((const float4*)b1)[slice * 4 + li];
    float4 ww = ((const float4*)W2)[slice * 4 + li];
    float inv = 1.f / (csum + 1e-16f);
    float t = fmaxf(fmaf(acc.x, inv, bb.x), 0.f) * ww.x
            + fmaxf(fmaf(acc.y, inv, bb.y), 0.f) * ww.y
            + fmaxf(fmaf(acc.z, inv, bb.z), 0.f) * ww.z
            + fmaxf(fmaf(acc.w, inv, bb.w), 0.f) * ww.w;
    t += __shfl_xor(t, 1);
    t += __shfl_xor(t, 2);
    if (lane == 0) atomicAdd(&xw2[d], t);
}

// ---------------- layer 2: scalar GAT head, 4 dsts/wave x 16 lanes ----------------
__global__ __launch_bounds__(256) void k_layer2(const float* __restrict__ xw2,
                                                const int* __restrict__ row_ptr,
                                                const int* __restrict__ csr_src,
                                                const float* __restrict__ att_src2,
                                                const float* __restrict__ att_dst2,
                                                const float* __restrict__ b2,
                                                float* __restrict__ out, int N)
{
    int grp  = (blockIdx.x * blockDim.x + threadIdx.x) >> 6;
    int lane = threadIdx.x & 63;
    int sub  = lane >> 4, li = lane & 15;
    int d    = grp * 4 + sub;
    if (d >= N) return;                       // whole 16-lane group uniform in d
    float as2  = att_src2[0];
    float adst = xw2[d] * att_dst2[0];
    float l = 0.f, acc = 0.f;
    int beg = row_ptr[d], end = row_ptr[d + 1];
    for (int j = beg + li; j < end; j += 16) {
        int s = csr_src[j];
        float xs = xw2[s];
        float p = __expf(lrelu(fmaf(xs, as2, adst)));
        l += p;
        acc = fmaf(p, xs, acc);
    }
    #pragma unroll
    for (int off = 1; off < 16; off <<= 1) {  // reduce within the 16-lane group
        l   += __shfl_xor(l, off);
        acc += __shfl_xor(acc, off);
    }
    if (li == 0) out[d] = acc / (l + 1e-16f) + b2[0];
}

extern "C" void kernel_launch(void* const* d_in, const int* in_sizes, int n_in,
                              void* d_out, int out_size, void* d_ws, size_t ws_size,
                              hipStream_t stream)
{
    const float* x        = (const float*)d_in[0];
    const int*   ei       = (const int*)d_in[1];
    const float* W1       = (const float*)d_in[2];
    const float* att_src1 = (const float*)d_in[3];
    const float* att_dst1 = (const float*)d_in[4];
    const float* b1       = (const float*)d_in[5];
    const float* W2       = (const float*)d_in[6];
    const float* att_src2 = (const float*)d_in[7];
    const float* att_dst2 = (const float*)d_in[8];
    const float* b2       = (const float*)d_in[9];
    float* out = (float*)d_out;

    const int N  = in_sizes[0] / 128;
    const int E  = in_sizes[1] / 2;
    const int Et = E + N;

    int R = 1024;                              // scan chunk; nblk <= 64
    while ((N + R - 1) / R > 64) R += 1024;
    const int nblk = (N + R - 1) / R;

    char* p = (char*)d_ws;
    auto alloc = [&](size_t bytes) {
        char* r = p;
        p += (bytes + 255) & ~(size_t)255;
        return (void*)r;
    };
    float* xw      = (float*)alloc((size_t)N * 128 * 4);   // slice-major [8][N][16]
    float* as_h    = (float*)alloc((size_t)4 * N * 4);     // head-major [4][N]
    float* a_dst   = (float*)alloc((size_t)N * 4 * 4);     // [N][4]
    float* xw2     = (float*)alloc((size_t)N * 4);
    int*   deg     = (int*)alloc((size_t)N * 4);
    int*   row_ptr = (int*)alloc((size_t)(N + 1) * 4);
    int*   cursor  = (int*)alloc((size_t)N * 4);
    int*   partial = (int*)alloc((size_t)64 * 4);
    int*   csr_src = (int*)alloc((size_t)Et * 4);

    hipMemsetAsync(deg, 0, (size_t)N * 4, stream);
    hipMemsetAsync(xw2, 0, (size_t)N * 4, stream);

    k_gemm1  <<<(N + 63) / 64,    256,  0, stream>>>(x, W1, att_src1, att_dst1,
                                                     xw, as_h, a_dst, N);
    k_count  <<<(Et + 255) / 256, 256,  0, stream>>>(ei, E, N, deg);
    k_scanA  <<<nblk,             1024, 0, stream>>>(deg, partial, N, R);
    k_scanB  <<<1,                64,   0, stream>>>(partial, nblk, row_ptr, N);
    k_scanC  <<<nblk,             1024, 0, stream>>>(deg, partial, row_ptr, cursor, N, R);
    k_scatter<<<(Et + 255) / 256, 256,  0, stream>>>(ei, E, N, cursor, csr_src, Et);
    k_agg    <<<((N + 3) / 4) * 8, 256, 0, stream>>>(xw, as_h, a_dst, row_ptr, csr_src,
                                                     b1, W2, xw2, N);
    k_layer2 <<<(N + 15) / 16,    256,  0, stream>>>(xw2, row_ptr, csr_src, att_src2,
                                                     att_dst2, b2, out, N);
}